// Round 6
// baseline (602.249 us; speedup 1.0000x reference)
//
#include <hip/hip_runtime.h>

#define N_NODES 100000
#define N_EDGES 1600000
#define HID 128
#define IN_DIM 5
#define XT_PITCH 132  // multiple of 4 (b128 alignment); 33 octets -> no rg conflict
#define BIN_SHIFT 9
#define BIN_NODES (1 << BIN_SHIFT)                     // 512
#define NBINS ((N_NODES + BIN_NODES - 1) / BIN_NODES)  // 196
#define NBLK_P 256                                     // edge-chunk blocks
#define EPB ((N_EDGES + NBLK_P - 1) / NBLK_P)          // 6250 edges per chunk
#define STAGE_CAP 12288                                // 48KB LDS stage per bin

// ---------------- CSR build (atomic-free in global memory) ----------------

__global__ __launch_bounds__(256) void k_hist(const int* __restrict__ ei,
                                              int* __restrict__ cnt) {
    __shared__ int h[NBINS];
    int t = threadIdx.x, b = blockIdx.x;
    for (int i = t; i < NBINS; i += 256) h[i] = 0;
    __syncthreads();
    int e0 = b * EPB, e1 = e0 + EPB; if (e1 > N_EDGES) e1 = N_EDGES;
    for (int e = e0 + t; e < e1; e += 256)
        atomicAdd(&h[ei[N_EDGES + e] >> BIN_SHIFT], 1);
    __syncthreads();
    for (int i = t; i < NBINS; i += 256) cnt[b * NBINS + i] = h[i];
}

__global__ __launch_bounds__(256) void k_blkscan(const int* __restrict__ cnt,
                                                 int* __restrict__ ofs,
                                                 int* __restrict__ tot) {
    __shared__ int sm[NBLK_P];
    int bin = blockIdx.x, t = threadIdx.x;
    int v = cnt[t * NBINS + bin];
    sm[t] = v; __syncthreads();
    for (int off = 1; off < NBLK_P; off <<= 1) {
        int add = (t >= off) ? sm[t - off] : 0;
        __syncthreads();
        sm[t] += add;
        __syncthreads();
    }
    ofs[t * NBINS + bin] = sm[t] - v;
    if (t == NBLK_P - 1) tot[bin] = sm[t];
}

__global__ __launch_bounds__(256) void k_bin_scan(const int* __restrict__ tot,
                                                  int* __restrict__ bin_ofs) {
    __shared__ int sm[256];
    int t = threadIdx.x;
    int v = (t < NBINS) ? tot[t] : 0;
    sm[t] = v; __syncthreads();
    for (int off = 1; off < 256; off <<= 1) {
        int add = (t >= off) ? sm[t - off] : 0;
        __syncthreads();
        sm[t] += add;
        __syncthreads();
    }
    if (t < NBINS) bin_ofs[t] = sm[t] - v;
    if (t == 0) bin_ofs[NBINS] = N_EDGES;
}

__global__ __launch_bounds__(256) void k_scatter(const int* __restrict__ ei,
                                                 const int* __restrict__ ofs,
                                                 const int* __restrict__ bin_ofs,
                                                 int* __restrict__ bin_buf) {
    __shared__ int base[NBINS];
    __shared__ int lcnt[NBINS];
    int t = threadIdx.x, b = blockIdx.x;
    for (int i = t; i < NBINS; i += 256) {
        base[i] = bin_ofs[i] + ofs[b * NBINS + i];
        lcnt[i] = 0;
    }
    __syncthreads();
    int e0 = b * EPB, e1 = e0 + EPB; if (e1 > N_EDGES) e1 = N_EDGES;
    for (int e = e0 + t; e < e1; e += 256) {
        int s = ei[e], d = ei[N_EDGES + e];
        int bin = d >> BIN_SHIFT;
        int p = atomicAdd(&lcnt[bin], 1);
        bin_buf[base[bin] + p] = (s << BIN_SHIFT) | (d & (BIN_NODES - 1));
    }
}

__global__ __launch_bounds__(256) void k_fill2(const int* __restrict__ bin_buf,
                                               const int* __restrict__ bin_ofs,
                                               int* __restrict__ row_ptr,
                                               float* __restrict__ dinv,
                                               int* __restrict__ col) {
    __shared__ int cnt[BIN_NODES];
    __shared__ int excl[BIN_NODES];
    __shared__ int ps[256];
    __shared__ int stage[STAGE_CAP];
    int t = threadIdx.x, b = blockIdx.x;
    int node_base = b * BIN_NODES;
    int node_cnt = N_NODES - node_base; if (node_cnt > BIN_NODES) node_cnt = BIN_NODES;
    for (int i = t; i < BIN_NODES; i += 256) cnt[i] = 0;
    __syncthreads();
    int e0 = bin_ofs[b], e1 = bin_ofs[b + 1];
    for (int e = e0 + t; e < e1; e += 256)
        atomicAdd(&cnt[bin_buf[e] & (BIN_NODES - 1)], 1);
    __syncthreads();
    int a0 = cnt[2 * t], a1 = cnt[2 * t + 1];
    int psum = a0 + a1;
    ps[t] = psum; __syncthreads();
    for (int off = 1; off < 256; off <<= 1) {
        int add = (t >= off) ? ps[t - off] : 0;
        __syncthreads();
        ps[t] += add;
        __syncthreads();
    }
    int tbase = ps[t] - psum;
    excl[2 * t] = tbase;
    excl[2 * t + 1] = tbase + a0;
    __syncthreads();
    int row_base = bin_ofs[b];
    for (int i = t; i < node_cnt; i += 256) {
        row_ptr[node_base + i] = row_base + excl[i];
        dinv[node_base + i] = rsqrtf((float)(cnt[i] + 1));  // +1 self-loop
    }
    if (b == NBINS - 1 && t == 0) row_ptr[N_NODES] = N_EDGES;
    __syncthreads();
    for (int i = t; i < BIN_NODES; i += 256) cnt[i] = excl[i];  // -> cursors
    __syncthreads();
    for (int e = e0 + t; e < e1; e += 256) {
        int v = bin_buf[e];
        int p = atomicAdd(&cnt[v & (BIN_NODES - 1)], 1);
        int lsrc = v >> BIN_SHIFT;
        if (p < STAGE_CAP) stage[p] = lsrc;
        else col[row_base + p] = lsrc;
    }
    __syncthreads();
    int tote = e1 - e0; if (tote > STAGE_CAP) tote = STAGE_CAP;
    for (int i = t; i < tote; i += 256) col[row_base + i] = stage[i];
}

// ---------------- layer 1: xd = dinv*x ; sx = A'xd ; h1 = relu(dinv*(sx W1)+b1) --

__global__ void k_xd(const float* __restrict__ x, const float* __restrict__ dinv,
                     float* __restrict__ xd) {
    int i = blockIdx.x * 256 + threadIdx.x;
    if (i < N_NODES * IN_DIM) xd[i] = x[i] * dinv[i / IN_DIM];
}

__global__ __launch_bounds__(256) void k_agg_x(const float* __restrict__ xd,
                                               const int* __restrict__ row_ptr,
                                               const int* __restrict__ col,
                                               float* __restrict__ sx) {
    int gw   = (blockIdx.x * 256 + threadIdx.x) >> 6;
    int lane = threadIdx.x & 63;
    int grp  = lane >> 3;
    int f    = lane & 7;
    int node = gw * 8 + grp;
    if (node >= N_NODES) return;
    bool act = (f < IN_DIM);
    float acc = act ? xd[node * IN_DIM + f] : 0.f;
    int j = row_ptr[node], end = row_ptr[node + 1];
    for (; j + 4 <= end; j += 4) {
        int s0 = col[j], s1 = col[j + 1], s2 = col[j + 2], s3 = col[j + 3];
        if (act) {
            float v0 = xd[s0 * IN_DIM + f];
            float v1 = xd[s1 * IN_DIM + f];
            float v2 = xd[s2 * IN_DIM + f];
            float v3 = xd[s3 * IN_DIM + f];
            acc += (v0 + v1) + (v2 + v3);
        }
    }
    for (; j < end; ++j) {
        int s = col[j];
        if (act) acc += xd[s * IN_DIM + f];
    }
    if (act) sx[node * IN_DIM + f] = acc;
}

__global__ void k_mm1f(const float* __restrict__ sx, const float* __restrict__ W1,
                       const float* __restrict__ b1, const float* __restrict__ dinv,
                       float* __restrict__ h) {
    __shared__ float Wl[IN_DIM * HID];
    __shared__ float bl[HID];
    int t = threadIdx.x;
    for (int j = t; j < IN_DIM * HID; j += 256) Wl[j] = W1[j];
    for (int j = t; j < HID; j += 256) bl[j] = b1[j];
    __syncthreads();
    int row = blockIdx.x * 2 + (t >> 7);
    int cc  = t & 127;
    float acc = 0.f;
    #pragma unroll
    for (int k = 0; k < IN_DIM; ++k)
        acc += sx[row * IN_DIM + k] * Wl[k * HID + cc];
    h[(size_t)row * HID + cc] = fmaxf(fmaf(dinv[row], acc, bl[cc]), 0.f);
}

// ---------------- hidden matmul (128x128): G = dinv * (X @ W) ----------------
// 64 rows/block, W quarter-staged TRANSPOSED (WlT[c4][kk], pitch 33 f4 -> no
// 4-way bank conflict), thread = 4 rows x cols {4cg..4cg+3, 64+4cg..64+4cg+3}.
// LDS 49.5KB -> 3 blocks/CU.

__global__ __launch_bounds__(256, 3) void k_mm_hid(const float* __restrict__ X,
                                                   const float* __restrict__ W,
                                                   const float* __restrict__ dinv,
                                                   float* __restrict__ G) {
    __shared__ float xt[64 * XT_PITCH];   // 33.8KB
    __shared__ float4 WlT[32 * 33];       // 16.9KB: WlT[c4*33 + kk], kk of phase
    int t = threadIdx.x;
    int row0 = blockIdx.x * 64;
    const float4* X4 = (const float4*)X;
    #pragma unroll
    for (int i = 0; i < 8; ++i) {
        int fidx = i * 256 + t;
        int r = fidx >> 5, c = fidx & 31;
        float4 v = {0.f, 0.f, 0.f, 0.f};
        if (row0 + r < N_NODES) v = X4[(size_t)(row0 + r) * 32 + c];
        *(float4*)&xt[r * XT_PITCH + c * 4] = v;
    }
    const float4* Wg4 = (const float4*)W;
    int cg = t & 15, rg = t >> 4;
    float4 acc[4][2] = {};
    for (int ph = 0; ph < 4; ++ph) {
        __syncthreads();  // xt ready (ph=0) / prev-phase compute done
        #pragma unroll
        for (int i = 0; i < 4; ++i) {
            int fidx = i * 256 + t;            // 0..1023
            int kk = fidx >> 5, c4 = fidx & 31;
            WlT[c4 * 33 + kk] = Wg4[(ph * 32 + kk) * 32 + c4];
        }
        __syncthreads();
        #pragma unroll 2
        for (int kk4 = 0; kk4 < 32; kk4 += 4) {
            float4 xr[4];
            #pragma unroll
            for (int r = 0; r < 4; ++r)
                xr[r] = *(const float4*)&xt[(rg * 4 + r) * XT_PITCH + ph * 32 + kk4];
            #pragma unroll
            for (int q = 0; q < 4; ++q) {
                float4 w0 = WlT[cg * 33 + kk4 + q];
                float4 w1 = WlT[(cg + 16) * 33 + kk4 + q];
                #pragma unroll
                for (int r = 0; r < 4; ++r) {
                    float xv = (q == 0) ? xr[r].x : (q == 1) ? xr[r].y
                             : (q == 2) ? xr[r].z : xr[r].w;
                    acc[r][0].x += xv * w0.x; acc[r][0].y += xv * w0.y;
                    acc[r][0].z += xv * w0.z; acc[r][0].w += xv * w0.w;
                    acc[r][1].x += xv * w1.x; acc[r][1].y += xv * w1.y;
                    acc[r][1].z += xv * w1.z; acc[r][1].w += xv * w1.w;
                }
            }
        }
    }
    #pragma unroll
    for (int r = 0; r < 4; ++r) {
        int row = row0 + rg * 4 + r;
        if (row < N_NODES) {
            float s = dinv[row];
            float4 a0 = acc[r][0], a1 = acc[r][1];
            a0.x *= s; a0.y *= s; a0.z *= s; a0.w *= s;
            a1.x *= s; a1.y *= s; a1.z *= s; a1.w *= s;
            *(float4*)(G + (size_t)row * HID + cg * 4)      = a0;  // cols 4cg..
            *(float4*)(G + (size_t)row * HID + 64 + cg * 4) = a1;  // cols 64+4cg..
        }
    }
}

// ---------------- quarter-feature aggregation ----------------
// Pass Q handles features [Q*32, Q*32+32): per-pass gather working set 12.8MB
// (L2-resident target). Wave = 1 node; half-waves gather 2 src rows x 128B.
// FINAL=1: per-pass partial FC dot -> partials[Q*N + node].

template <int FINAL>
__global__ __launch_bounds__(256) void k_agg_q(const float* __restrict__ g,
                                               const int* __restrict__ row_ptr,
                                               const int* __restrict__ col,
                                               const float* __restrict__ dinv,
                                               const float* __restrict__ bias,
                                               const float* __restrict__ Wfc,
                                               float* __restrict__ outp, int Q) {
    int lane = threadIdx.x & 63;
    int w    = threadIdx.x >> 6;
    int node = blockIdx.x * 4 + w;   // grid exact: 25000*4
    int h = lane >> 5, f = lane & 31;
    int qoff = Q * 32;
    const float* gq = g + qoff;
    float acc = (h == 0) ? gq[(size_t)node * HID + f] : 0.f;  // self term
    int start = row_ptr[node], end = row_ptr[node + 1];
    int idx = start + lane;
    int myc = (idx < end) ? col[idx] : 0;
    for (int j0 = start; j0 < end; j0 += 64) {
        int cur = myc;
        if (j0 + 64 < end) {
            int nidx = j0 + 64 + lane;
            myc = (nidx < end) ? col[nidx] : 0;
        }
        int cnt = end - j0; if (cnt > 64) cnt = 64;
        int jj = 0;
        for (; jj + 16 <= cnt; jj += 16) {   // 8 pairs in flight
            int s[8];
            #pragma unroll
            for (int q = 0; q < 8; ++q) s[q] = __shfl(cur, jj + 2 * q + h);
            float v[8];
            #pragma unroll
            for (int q = 0; q < 8; ++q) v[q] = gq[(size_t)s[q] * HID + f];
            acc += ((v[0] + v[1]) + (v[2] + v[3])) + ((v[4] + v[5]) + (v[6] + v[7]));
        }
        for (; jj + 2 <= cnt; jj += 2) {
            int s = __shfl(cur, jj + h);
            acc += gq[(size_t)s * HID + f];
        }
        if (jj < cnt) {                      // odd tail: half 0 only
            int s = __shfl(cur, jj);
            if (h == 0) acc += gq[(size_t)s * HID + f];
        }
    }
    acc += __shfl_xor(acc, 32, 64);          // combine halves (symmetric result)
    float val = fmaxf(fmaf(dinv[node], acc, bias[qoff + f]), 0.f);
    if (FINAL == 0) {
        if (h == 0) outp[(size_t)node * HID + qoff + f] = val;
    } else {
        float d = val * Wfc[qoff + f];
        #pragma unroll
        for (int off = 16; off > 0; off >>= 1) d += __shfl_down(d, off, 32);
        if (lane == 0) outp[(size_t)Q * N_NODES + node] = d;
    }
}

__global__ void k_fcred(const float* __restrict__ partials,
                        const float* __restrict__ bfc, float* __restrict__ out) {
    int i = blockIdx.x * 256 + threadIdx.x;
    if (i < N_NODES)
        out[i] = ((partials[i] + partials[N_NODES + i]) +
                  (partials[2 * N_NODES + i] + partials[3 * N_NODES + i])) + bfc[0];
}

// ---------------- launcher ----------------

extern "C" void kernel_launch(void* const* d_in, const int* in_sizes, int n_in,
                              void* d_out, int out_size, void* d_ws, size_t ws_size,
                              hipStream_t stream) {
    (void)in_sizes; (void)n_in; (void)out_size; (void)ws_size;
    const float* x   = (const float*)d_in[0];
    const int*   ei  = (const int*)d_in[1];
    const float* W1  = (const float*)d_in[2];
    const float* b1  = (const float*)d_in[3];
    const float* W2  = (const float*)d_in[4];
    const float* b2  = (const float*)d_in[5];
    const float* W3  = (const float*)d_in[6];
    const float* b3  = (const float*)d_in[7];
    const float* Wfc = (const float*)d_in[8];
    const float* bfc = (const float*)d_in[9];
    float* out = (float*)d_out;

    char* p = (char*)d_ws;
    auto alloc = [&](size_t bytes) -> void* {
        void* r = (void*)p;
        p += (bytes + 511) & ~(size_t)511;
        return r;
    };
    float* dinv     = (float*)alloc((size_t)N_NODES * 4);
    int*   row_ptr  = (int*)  alloc((size_t)(N_NODES + 1) * 4);
    int*   cnt      = (int*)  alloc((size_t)NBLK_P * NBINS * 4);
    int*   ofs      = (int*)  alloc((size_t)NBLK_P * NBINS * 4);
    int*   tot      = (int*)  alloc((size_t)NBINS * 4);
    int*   bin_ofs  = (int*)  alloc((size_t)(NBINS + 1) * 4);
    int*   col      = (int*)  alloc((size_t)N_EDGES * 4);
    float* partials = (float*)alloc((size_t)4 * N_NODES * 4);
    float* bufA     = (float*)alloc((size_t)N_NODES * HID * 4);
    float* bufB     = (float*)alloc((size_t)N_NODES * HID * 4);
    // lifetime-disjoint aliases inside bufA (first live at layer-2 mm output):
    int*   bin_buf = (int*)bufA;              // dead after k_fill2
    float* xd      = (float*)bufA;            // 2MB, live k_xd..k_agg_x
    float* sx      = (float*)bufA + 512000;   // 2MB, live k_agg_x..k_mm1f

    // CSR build — no global atomics, no memsets
    k_hist   <<<NBLK_P, 256, 0, stream>>>(ei, cnt);
    k_blkscan<<<NBINS, 256, 0, stream>>>(cnt, ofs, tot);
    k_bin_scan<<<1, 256, 0, stream>>>(tot, bin_ofs);
    k_scatter<<<NBLK_P, 256, 0, stream>>>(ei, ofs, bin_ofs, bin_buf);
    k_fill2  <<<NBINS, 256, 0, stream>>>(bin_buf, bin_ofs, row_ptr, dinv, col);

    int mm_blocks = (N_NODES + 63) / 64;  // 1563

    // layer 1: aggregate 5-wide first (A(xd)W1 == A(xd W1)), then fused mm
    k_xd   <<<(N_NODES * IN_DIM + 255) / 256, 256, 0, stream>>>(x, dinv, xd);
    k_agg_x<<<(N_NODES + 31) / 32, 256, 0, stream>>>(xd, row_ptr, col, sx);
    k_mm1f <<<N_NODES / 2, 256, 0, stream>>>(sx, W1, b1, dinv, bufB);

    // layer 2
    k_mm_hid<<<mm_blocks, 256, 0, stream>>>(bufB, W2, dinv, bufA);
    for (int q = 0; q < 4; ++q)
        k_agg_q<0><<<N_NODES / 4, 256, 0, stream>>>(bufA, row_ptr, col, dinv, b2,
                                                    nullptr, bufB, q);
    // layer 3 + fused FC (per-quarter partial dots, then reduce)
    k_mm_hid<<<mm_blocks, 256, 0, stream>>>(bufB, W3, dinv, bufA);
    for (int q = 0; q < 4; ++q)
        k_agg_q<1><<<N_NODES / 4, 256, 0, stream>>>(bufA, row_ptr, col, dinv, b3,
                                                    Wfc, partials, q);
    k_fcred<<<(N_NODES + 255) / 256, 256, 0, stream>>>(partials, bfc, out);
}

// Round 7
// 442.527 us; speedup vs baseline: 1.3609x; 1.3609x over previous
//
#include <hip/hip_runtime.h>

#define N_NODES 100000
#define N_EDGES 1600000
#define HID 128
#define IN_DIM 5
#define XT_PITCH 132  // 16B-aligned rows; row stride mod 32 banks != 0
#define BIN_SHIFT 9
#define BIN_NODES (1 << BIN_SHIFT)                     // 512
#define NBINS ((N_NODES + BIN_NODES - 1) / BIN_NODES)  // 196
#define NBLK_P 256                                     // edge-chunk blocks
#define EPB ((N_EDGES + NBLK_P - 1) / NBLK_P)          // 6250 edges per chunk
#define STAGE_CAP 12288                                // 48KB LDS stage per bin

// ---------------- CSR build (atomic-free in global memory) ----------------

__global__ __launch_bounds__(256) void k_hist(const int* __restrict__ ei,
                                              int* __restrict__ cnt) {
    __shared__ int h[NBINS];
    int t = threadIdx.x, b = blockIdx.x;
    for (int i = t; i < NBINS; i += 256) h[i] = 0;
    __syncthreads();
    int e0 = b * EPB, e1 = e0 + EPB; if (e1 > N_EDGES) e1 = N_EDGES;
    for (int e = e0 + t; e < e1; e += 256)
        atomicAdd(&h[ei[N_EDGES + e] >> BIN_SHIFT], 1);
    __syncthreads();
    for (int i = t; i < NBINS; i += 256) cnt[b * NBINS + i] = h[i];
}

__global__ __launch_bounds__(256) void k_blkscan(const int* __restrict__ cnt,
                                                 int* __restrict__ ofs,
                                                 int* __restrict__ tot) {
    __shared__ int sm[NBLK_P];
    int bin = blockIdx.x, t = threadIdx.x;
    int v = cnt[t * NBINS + bin];
    sm[t] = v; __syncthreads();
    for (int off = 1; off < NBLK_P; off <<= 1) {
        int add = (t >= off) ? sm[t - off] : 0;
        __syncthreads();
        sm[t] += add;
        __syncthreads();
    }
    ofs[t * NBINS + bin] = sm[t] - v;
    if (t == NBLK_P - 1) tot[bin] = sm[t];
}

__global__ __launch_bounds__(256) void k_bin_scan(const int* __restrict__ tot,
                                                  int* __restrict__ bin_ofs) {
    __shared__ int sm[256];
    int t = threadIdx.x;
    int v = (t < NBINS) ? tot[t] : 0;
    sm[t] = v; __syncthreads();
    for (int off = 1; off < 256; off <<= 1) {
        int add = (t >= off) ? sm[t - off] : 0;
        __syncthreads();
        sm[t] += add;
        __syncthreads();
    }
    if (t < NBINS) bin_ofs[t] = sm[t] - v;
    if (t == 0) bin_ofs[NBINS] = N_EDGES;
}

__global__ __launch_bounds__(256) void k_scatter(const int* __restrict__ ei,
                                                 const int* __restrict__ ofs,
                                                 const int* __restrict__ bin_ofs,
                                                 int* __restrict__ bin_buf) {
    __shared__ int base[NBINS];
    __shared__ int lcnt[NBINS];
    int t = threadIdx.x, b = blockIdx.x;
    for (int i = t; i < NBINS; i += 256) {
        base[i] = bin_ofs[i] + ofs[b * NBINS + i];
        lcnt[i] = 0;
    }
    __syncthreads();
    int e0 = b * EPB, e1 = e0 + EPB; if (e1 > N_EDGES) e1 = N_EDGES;
    for (int e = e0 + t; e < e1; e += 256) {
        int s = ei[e], d = ei[N_EDGES + e];
        int bin = d >> BIN_SHIFT;
        int p = atomicAdd(&lcnt[bin], 1);
        bin_buf[base[bin] + p] = (s << BIN_SHIFT) | (d & (BIN_NODES - 1));
    }
}

__global__ __launch_bounds__(256) void k_fill2(const int* __restrict__ bin_buf,
                                               const int* __restrict__ bin_ofs,
                                               int* __restrict__ row_ptr,
                                               float* __restrict__ dinv,
                                               int* __restrict__ col) {
    __shared__ int cnt[BIN_NODES];
    __shared__ int excl[BIN_NODES];
    __shared__ int ps[256];
    __shared__ int stage[STAGE_CAP];
    int t = threadIdx.x, b = blockIdx.x;
    int node_base = b * BIN_NODES;
    int node_cnt = N_NODES - node_base; if (node_cnt > BIN_NODES) node_cnt = BIN_NODES;
    for (int i = t; i < BIN_NODES; i += 256) cnt[i] = 0;
    __syncthreads();
    int e0 = bin_ofs[b], e1 = bin_ofs[b + 1];
    for (int e = e0 + t; e < e1; e += 256)
        atomicAdd(&cnt[bin_buf[e] & (BIN_NODES - 1)], 1);
    __syncthreads();
    int a0 = cnt[2 * t], a1 = cnt[2 * t + 1];
    int psum = a0 + a1;
    ps[t] = psum; __syncthreads();
    for (int off = 1; off < 256; off <<= 1) {
        int add = (t >= off) ? ps[t - off] : 0;
        __syncthreads();
        ps[t] += add;
        __syncthreads();
    }
    int tbase = ps[t] - psum;
    excl[2 * t] = tbase;
    excl[2 * t + 1] = tbase + a0;
    __syncthreads();
    int row_base = bin_ofs[b];
    for (int i = t; i < node_cnt; i += 256) {
        row_ptr[node_base + i] = row_base + excl[i];
        dinv[node_base + i] = rsqrtf((float)(cnt[i] + 1));  // +1 self-loop
    }
    if (b == NBINS - 1 && t == 0) row_ptr[N_NODES] = N_EDGES;
    __syncthreads();
    for (int i = t; i < BIN_NODES; i += 256) cnt[i] = excl[i];  // -> cursors
    __syncthreads();
    for (int e = e0 + t; e < e1; e += 256) {
        int v = bin_buf[e];
        int p = atomicAdd(&cnt[v & (BIN_NODES - 1)], 1);
        int lsrc = v >> BIN_SHIFT;
        if (p < STAGE_CAP) stage[p] = lsrc;
        else col[row_base + p] = lsrc;
    }
    __syncthreads();
    int tote = e1 - e0; if (tote > STAGE_CAP) tote = STAGE_CAP;
    for (int i = t; i < tote; i += 256) col[row_base + i] = stage[i];
}

// ---------------- layer 1: xd = dinv*x ; sx = A'xd ; h1 = relu(dinv*(sx W1)+b1) --

__global__ void k_xd(const float* __restrict__ x, const float* __restrict__ dinv,
                     float* __restrict__ xd) {
    int i = blockIdx.x * 256 + threadIdx.x;
    if (i < N_NODES * IN_DIM) xd[i] = x[i] * dinv[i / IN_DIM];
}

__global__ __launch_bounds__(256) void k_agg_x(const float* __restrict__ xd,
                                               const int* __restrict__ row_ptr,
                                               const int* __restrict__ col,
                                               float* __restrict__ sx) {
    int gw   = (blockIdx.x * 256 + threadIdx.x) >> 6;
    int lane = threadIdx.x & 63;
    int grp  = lane >> 3;
    int f    = lane & 7;
    int node = gw * 8 + grp;
    if (node >= N_NODES) return;
    bool act = (f < IN_DIM);
    float acc = act ? xd[node * IN_DIM + f] : 0.f;
    int j = row_ptr[node], end = row_ptr[node + 1];
    for (; j + 4 <= end; j += 4) {
        int s0 = col[j], s1 = col[j + 1], s2 = col[j + 2], s3 = col[j + 3];
        if (act) {
            float v0 = xd[s0 * IN_DIM + f];
            float v1 = xd[s1 * IN_DIM + f];
            float v2 = xd[s2 * IN_DIM + f];
            float v3 = xd[s3 * IN_DIM + f];
            acc += (v0 + v1) + (v2 + v3);
        }
    }
    for (; j < end; ++j) {
        int s = col[j];
        if (act) acc += xd[s * IN_DIM + f];
    }
    if (act) sx[node * IN_DIM + f] = acc;
}

__global__ void k_mm1f(const float* __restrict__ sx, const float* __restrict__ W1,
                       const float* __restrict__ b1, const float* __restrict__ dinv,
                       float* __restrict__ h) {
    __shared__ float Wl[IN_DIM * HID];
    __shared__ float bl[HID];
    int t = threadIdx.x;
    for (int j = t; j < IN_DIM * HID; j += 256) Wl[j] = W1[j];
    for (int j = t; j < HID; j += 256) bl[j] = b1[j];
    __syncthreads();
    int row = blockIdx.x * 2 + (t >> 7);
    int cc  = t & 127;
    float acc = 0.f;
    #pragma unroll
    for (int k = 0; k < IN_DIM; ++k)
        acc += sx[row * IN_DIM + k] * Wl[k * HID + cc];
    h[(size_t)row * HID + cc] = fmaxf(fmaf(dinv[row], acc, bl[cc]), 0.f);
}

// ---------------- hidden matmul (128x128): G = dinv * (X @ W) ----------------
// v3: 48 rows/block, 3 rows x 8 cols per thread, W staged transposed in
// 1/8-chunks (WlT[c4*17+kk], 8.7KB). LDS total 34KB -> 4 blocks/CU.

__global__ __launch_bounds__(256, 4) void k_mm_hid(const float* __restrict__ X,
                                                   const float* __restrict__ W,
                                                   const float* __restrict__ dinv,
                                                   float* __restrict__ G) {
    __shared__ float xt[48 * XT_PITCH];   // 25.3KB
    __shared__ float4 WlT[32 * 17];       // 8.7KB: WlT[c4*17 + kk], kk of chunk
    int t = threadIdx.x;
    int row0 = blockIdx.x * 48;
    const float4* X4 = (const float4*)X;
    #pragma unroll
    for (int i = 0; i < 6; ++i) {
        int fidx = i * 256 + t;            // 0..1535
        int r = fidx >> 5, c = fidx & 31;
        float4 v = {0.f, 0.f, 0.f, 0.f};
        if (row0 + r < N_NODES) v = X4[(size_t)(row0 + r) * 32 + c];
        *(float4*)&xt[r * XT_PITCH + c * 4] = v;
    }
    const float4* Wg4 = (const float4*)W;
    int cg = t & 15, rg = t >> 4;         // rg 0..15 -> rows rg*3..rg*3+2
    float4 acc[3][2] = {};
    for (int ph = 0; ph < 8; ++ph) {
        __syncthreads();  // xt ready (ph=0) / prev-chunk compute done
        #pragma unroll
        for (int i = 0; i < 2; ++i) {
            int fidx = i * 256 + t;        // 0..511
            int kk = fidx >> 5, c4 = fidx & 31;
            WlT[c4 * 17 + kk] = Wg4[(ph * 16 + kk) * 32 + c4];
        }
        __syncthreads();
        #pragma unroll
        for (int kk4 = 0; kk4 < 16; kk4 += 4) {
            float4 xr[3];
            #pragma unroll
            for (int r = 0; r < 3; ++r)
                xr[r] = *(const float4*)&xt[(rg * 3 + r) * XT_PITCH + ph * 16 + kk4];
            #pragma unroll
            for (int q = 0; q < 4; ++q) {
                float4 w0 = WlT[cg * 17 + kk4 + q];
                float4 w1 = WlT[(cg + 16) * 17 + kk4 + q];
                #pragma unroll
                for (int r = 0; r < 3; ++r) {
                    float xv = (q == 0) ? xr[r].x : (q == 1) ? xr[r].y
                             : (q == 2) ? xr[r].z : xr[r].w;
                    acc[r][0].x += xv * w0.x; acc[r][0].y += xv * w0.y;
                    acc[r][0].z += xv * w0.z; acc[r][0].w += xv * w0.w;
                    acc[r][1].x += xv * w1.x; acc[r][1].y += xv * w1.y;
                    acc[r][1].z += xv * w1.z; acc[r][1].w += xv * w1.w;
                }
            }
        }
    }
    #pragma unroll
    for (int r = 0; r < 3; ++r) {
        int row = row0 + rg * 3 + r;
        if (row < N_NODES) {
            float s = dinv[row];
            float4 a0 = acc[r][0], a1 = acc[r][1];
            a0.x *= s; a0.y *= s; a0.z *= s; a0.w *= s;
            a1.x *= s; a1.y *= s; a1.z *= s; a1.w *= s;
            *(float4*)(G + (size_t)row * HID + cg * 4)      = a0;  // cols 4cg..
            *(float4*)(G + (size_t)row * HID + 64 + cg * 4) = a1;  // cols 64+4cg..
        }
    }
}

// ---------------- aggregation: out = relu(dinv*(g[i] + sum g[src]) + b) ------
// 1 wave per node, float2 per lane (512B/gather). col chunk prefetch; MLP 8.
// (round-4 version: 28 VGPR, ~75% occupancy — best measured at 119us/layer)

template <int FINAL>
__global__ __launch_bounds__(256) void k_agg(const float* __restrict__ g,
                                             const int* __restrict__ row_ptr,
                                             const int* __restrict__ col,
                                             const float* __restrict__ dinv,
                                             const float* __restrict__ bias,
                                             const float* __restrict__ Wfc,
                                             const float* __restrict__ bfc,
                                             float* __restrict__ out) {
    int lane = threadIdx.x & 63;
    int w    = threadIdx.x >> 6;
    int node = blockIdx.x * 4 + w;   // grid exact: 25000*4 = 100000
    const float2* g2 = (const float2*)g;
    float2 sacc = g2[(size_t)node * 64 + lane];  // self-loop term
    float ax = sacc.x, ay = sacc.y;
    int start = row_ptr[node], end = row_ptr[node + 1];
    int idx = start + lane;
    int myc = (idx < end) ? col[idx] : 0;
    for (int j0 = start; j0 < end; j0 += 64) {
        int cur = myc;
        if (j0 + 64 < end) {
            int nidx = j0 + 64 + lane;
            myc = (nidx < end) ? col[nidx] : 0;
        }
        int cnt = end - j0; if (cnt > 64) cnt = 64;
        int jj = 0;
        for (; jj + 8 <= cnt; jj += 8) {
            int s0 = __shfl(cur, jj);     int s1 = __shfl(cur, jj + 1);
            int s2 = __shfl(cur, jj + 2); int s3 = __shfl(cur, jj + 3);
            int s4 = __shfl(cur, jj + 4); int s5 = __shfl(cur, jj + 5);
            int s6 = __shfl(cur, jj + 6); int s7 = __shfl(cur, jj + 7);
            float2 v0 = g2[(size_t)s0 * 64 + lane];
            float2 v1 = g2[(size_t)s1 * 64 + lane];
            float2 v2 = g2[(size_t)s2 * 64 + lane];
            float2 v3 = g2[(size_t)s3 * 64 + lane];
            float2 v4 = g2[(size_t)s4 * 64 + lane];
            float2 v5 = g2[(size_t)s5 * 64 + lane];
            float2 v6 = g2[(size_t)s6 * 64 + lane];
            float2 v7 = g2[(size_t)s7 * 64 + lane];
            ax += ((v0.x + v1.x) + (v2.x + v3.x)) + ((v4.x + v5.x) + (v6.x + v7.x));
            ay += ((v0.y + v1.y) + (v2.y + v3.y)) + ((v4.y + v5.y) + (v6.y + v7.y));
        }
        for (; jj + 4 <= cnt; jj += 4) {
            int s0 = __shfl(cur, jj);     int s1 = __shfl(cur, jj + 1);
            int s2 = __shfl(cur, jj + 2); int s3 = __shfl(cur, jj + 3);
            float2 v0 = g2[(size_t)s0 * 64 + lane];
            float2 v1 = g2[(size_t)s1 * 64 + lane];
            float2 v2 = g2[(size_t)s2 * 64 + lane];
            float2 v3 = g2[(size_t)s3 * 64 + lane];
            ax += (v0.x + v1.x) + (v2.x + v3.x);
            ay += (v0.y + v1.y) + (v2.y + v3.y);
        }
        for (; jj < cnt; ++jj) {
            int s = __shfl(cur, jj);
            float2 v = g2[(size_t)s * 64 + lane];
            ax += v.x; ay += v.y;
        }
    }
    float sc = dinv[node];
    float2 bb = *(const float2*)(bias + lane * 2);
    float o0 = fmaxf(fmaf(sc, ax, bb.x), 0.f);
    float o1 = fmaxf(fmaf(sc, ay, bb.y), 0.f);
    if (FINAL == 0) {
        *(float2*)(out + (size_t)node * HID + lane * 2) = make_float2(o0, o1);
    } else {
        float2 wv = *(const float2*)(Wfc + lane * 2);
        float d = o0 * wv.x + o1 * wv.y;
        #pragma unroll
        for (int off = 32; off > 0; off >>= 1) d += __shfl_down(d, off, 64);
        if (lane == 0) out[node] = d + bfc[0];
    }
}

// ---------------- launcher ----------------

extern "C" void kernel_launch(void* const* d_in, const int* in_sizes, int n_in,
                              void* d_out, int out_size, void* d_ws, size_t ws_size,
                              hipStream_t stream) {
    (void)in_sizes; (void)n_in; (void)out_size; (void)ws_size;
    const float* x   = (const float*)d_in[0];
    const int*   ei  = (const int*)d_in[1];
    const float* W1  = (const float*)d_in[2];
    const float* b1  = (const float*)d_in[3];
    const float* W2  = (const float*)d_in[4];
    const float* b2  = (const float*)d_in[5];
    const float* W3  = (const float*)d_in[6];
    const float* b3  = (const float*)d_in[7];
    const float* Wfc = (const float*)d_in[8];
    const float* bfc = (const float*)d_in[9];
    float* out = (float*)d_out;

    char* p = (char*)d_ws;
    auto alloc = [&](size_t bytes) -> void* {
        void* r = (void*)p;
        p += (bytes + 511) & ~(size_t)511;
        return r;
    };
    float* dinv     = (float*)alloc((size_t)N_NODES * 4);
    int*   row_ptr  = (int*)  alloc((size_t)(N_NODES + 1) * 4);
    int*   cnt      = (int*)  alloc((size_t)NBLK_P * NBINS * 4);
    int*   ofs      = (int*)  alloc((size_t)NBLK_P * NBINS * 4);
    int*   tot      = (int*)  alloc((size_t)NBINS * 4);
    int*   bin_ofs  = (int*)  alloc((size_t)(NBINS + 1) * 4);
    int*   col      = (int*)  alloc((size_t)N_EDGES * 4);
    float* bufA     = (float*)alloc((size_t)N_NODES * HID * 4);
    float* bufB     = (float*)alloc((size_t)N_NODES * HID * 4);
    // lifetime-disjoint aliases inside bufA (first live at layer-2 mm output):
    int*   bin_buf = (int*)bufA;              // dead after k_fill2
    float* xd      = (float*)bufA;            // 2MB, live k_xd..k_agg_x
    float* sx      = (float*)bufA + 512000;   // 2MB, live k_agg_x..k_mm1f

    // CSR build — no global atomics, no memsets
    k_hist   <<<NBLK_P, 256, 0, stream>>>(ei, cnt);
    k_blkscan<<<NBINS, 256, 0, stream>>>(cnt, ofs, tot);
    k_bin_scan<<<1, 256, 0, stream>>>(tot, bin_ofs);
    k_scatter<<<NBLK_P, 256, 0, stream>>>(ei, ofs, bin_ofs, bin_buf);
    k_fill2  <<<NBINS, 256, 0, stream>>>(bin_buf, bin_ofs, row_ptr, dinv, col);

    int mm_blocks = (N_NODES + 47) / 48;  // 2084

    // layer 1: aggregate 5-wide first (A(xd)W1 == A(xd W1)), then fused mm
    k_xd   <<<(N_NODES * IN_DIM + 255) / 256, 256, 0, stream>>>(x, dinv, xd);
    k_agg_x<<<(N_NODES + 31) / 32, 256, 0, stream>>>(xd, row_ptr, col, sx);
    k_mm1f <<<N_NODES / 2, 256, 0, stream>>>(sx, W1, b1, dinv, bufB);

    // layer 2
    k_mm_hid<<<mm_blocks, 256, 0, stream>>>(bufB, W2, dinv, bufA);
    k_agg<0><<<N_NODES / 4, 256, 0, stream>>>(bufA, row_ptr, col, dinv, b2,
                                              nullptr, nullptr, bufB);
    // layer 3 + fused FC
    k_mm_hid<<<mm_blocks, 256, 0, stream>>>(bufB, W3, dinv, bufA);
    k_agg<1><<<N_NODES / 4, 256, 0, stream>>>(bufA, row_ptr, col, dinv, b3,
                                              Wfc, bfc, out);
}